// Round 9
// baseline (230.531 us; speedup 1.0000x reference)
//
#include <hip/hip_runtime.h>
#include <math.h>

#define NI   32
#define NH   1024
#define NB   1024

// ws layout (floats). g-axis (h2 units) degree-SORTED (suffix skip); h1-axis NATURAL.
//   W1t [32][1056] : W1t[j][s] = m1-masked W1[orig(s)][j], s sorted (stride-padded)
//   b1s [1056]     : sorted b1 (overread lanes masked)
//   b2s [1024]     : sorted b2
//   W3s [64][1024] : m3-masked, sorted columns
//   W2t [1054][1024]: W2t[oh][sg] = m2-masked W2[orig(sg)][oh]; rows natural oh,
//                     +30 pad rows for u-overrun loads (x0.0, 0xAA = finite)
#define W1T_STRIDE 1056
#define OFF_W1T 0
#define OFF_B1S (32 * W1T_STRIDE)          // 33792
#define OFF_B2S (OFF_B1S + W1T_STRIDE)     // 34848
#define OFF_W3S (OFF_B2S + NH)             // 35872
#define OFF_W2T (OFF_W3S + 64 * NH)        // 101408
// total = 101408 + 1054*1024 = 1180704 floats (~4.72 MB)

// degree class d: units h = d, d+31, ... ; d=0 has 34 units, d>=1 has 33.
__device__ __forceinline__ int base_of(int d) { return (d == 0) ? 0 : 34 + 33 * (d - 1); }

// ---- prep: per-degree-class transpose; writes are >=132B-contiguous runs ----
template <int CNT>
__device__ __forceinline__ void prep_w2_cls(int d, int oh0, const float* __restrict__ W2,
                                            float* __restrict__ ws, int t,
                                            float (*tile)[257]) {
    const int bse = base_of(d);
#pragma unroll 1
    for (int p = 0; p < (CNT + 3) / 4; ++p) {       // coalesced reads of W2 rows (og class)
        int k = p * 4 + (t >> 6);
        if (k < CNT) {
            int og = d + 31 * k;
            float4 v = ((const float4*)(W2 + (size_t)og * NH + oh0))[t & 63];
            int c = (t & 63) * 4;
            tile[k][c] = v.x; tile[k][c + 1] = v.y;
            tile[k][c + 2] = v.z; tile[k][c + 3] = v.w;
        }
    }
    __syncthreads();
#pragma unroll 1
    for (int it = 0; it < CNT; ++it) {              // writes: runs of CNT contiguous floats
        int e = it * 256 + t;
        int oh_l = e / CNT;                         // const divide -> magic mul
        int k = e - oh_l * CNT;
        int oh = oh0 + oh_l;
        float v = (d >= (oh % 31)) ? tile[k][oh_l] : 0.0f;
        ws[OFF_W2T + (size_t)oh * NH + bse + k] = v;
    }
}

template <int CNT>
__device__ __forceinline__ void prep_small_cls(int d, const float* __restrict__ W1,
        const float* __restrict__ b1, const float* __restrict__ b2,
        const float* __restrict__ W3, float* __restrict__ ws, int t) {
    const int bse = base_of(d);
#pragma unroll 1
    for (int e = t; e < 64 * CNT; e += 256) {       // W3s
        int o = e / CNT, k = e - o * CNT;
        int og = d + 31 * k;
        float v = (((o & 31) - 1) >= d) ? W3[(size_t)o * NH + og] : 0.0f;
        ws[OFF_W3S + (size_t)o * NH + bse + k] = v;
    }
#pragma unroll 1
    for (int e = t; e < 32 * CNT; e += 256) {       // W1t
        int j = e / CNT, k = e - j * CNT;
        int og = d + 31 * k;
        float v = (d >= j) ? W1[og * NI + j] : 0.0f;
        ws[OFF_W1T + j * W1T_STRIDE + bse + k] = v;
    }
    if (t < CNT) {                                  // biases
        int og = d + 31 * t;
        ws[OFF_B1S + bse + t] = b1[og];
        ws[OFF_B2S + bse + t] = b2[og];
    }
}

__global__ __launch_bounds__(256) void prep_all(const float* __restrict__ W1,
        const float* __restrict__ b1, const float* __restrict__ W2,
        const float* __restrict__ b2, const float* __restrict__ W3,
        float* __restrict__ ws) {
    __shared__ float tile[34][257];
    const int bid = blockIdx.x, t = threadIdx.x;
    if (bid < 124) {                                 // 31 classes x 4 oh-chunks
        int d = bid >> 2, oh0 = (bid & 3) * 256;
        if (d == 0) prep_w2_cls<34>(0, oh0, W2, ws, t, tile);
        else        prep_w2_cls<33>(d, oh0, W2, ws, t, tile);
    } else {                                         // 31 classes: W3s/W1t/biases
        int d = bid - 124;
        if (d == 0) prep_small_cls<34>(0, W1, b1, b2, W3, ws, t);
        else        prep_small_cls<33>(d, W1, b1, b2, W3, ws, t);
    }
}

// Block = 2 batch rows x 8 slice-waves (width 128, float2/lane). 512 blocks x
// 512 thr = 4096 waves = 4 waves/SIMD (2 independent blocks/CU). Phase A
// computed ONCE per block by wave 0 (B-idle from i>=5), shared via LDS; B's 34
// panel loads in 3 sched-fenced groups; a1 fetched via broadcast ds_read.
__global__ __launch_bounds__(512, 4) void made_scan(
        const float* __restrict__ inputs,
        const float* __restrict__ b3,
        const float* __restrict__ ws,
        float* __restrict__ out) {
    __shared__ float a1s[36][2];        // [unit u][row] — zero-padded to 36
    __shared__ float part[2][8][4];     // [buf][wave][s00,s01,s10,s11]

    const int lane = threadIdx.x & 63;
    const int w    = threadIdx.x >> 6;  // 0..7
    const int gb   = w * 128;           // sorted-g slice base
    const int row0 = blockIdx.x * 2;

    const float* W1t = ws + OFF_W1T;
    const float* b1s = ws + OFF_B1S;
    const float* b2s = ws + OFF_B2S;
    const float* W3s = ws + OFF_W3S;
    const float* W2t = ws + OFF_W2T;

    float2 acc0 = ((const float2*)(b2s + gb))[lane];   // z2 slice, rows 0/1
    float2 acc1 = acc0;
    float xin0 = (lane < NI) ? inputs[row0 * NI + lane] : 0.0f;
    float xin1 = (lane < NI) ? inputs[(row0 + 1) * NI + lane] : 0.0f;
    float b3v  = b3[lane];
    float xr0 = 0.f, xr1 = 0.f, J0 = 0.f, J1 = 0.f;    // x_j in lane j

#pragma unroll 1
    for (int i = 0; i < NI; ++i) {
        const int dd   = i - 1;
        const int goff = (i <= 1) ? 0 : (33 * i - 32);  // base(i-1)
        const int cnt  = (i == 1) ? 34 : 33;
        const int L    = 33 * i + 1;                    // base(i), i>=1
        const bool doB = (i > 0) && (gb + 128 > goff);
        const bool doC = (i > 0) && (gb < L);

        float2 wa = make_float2(0, 0), wb = make_float2(0, 0);
        if (doC) {                                      // C weights: issue early
            wa = ((const float2*)(W3s + (size_t)i * NH + gb))[lane];
            wb = ((const float2*)(W3s + (size_t)(NI + i) * NH + gb))[lane];
        }

        const float* rb = W2t + (size_t)((dd < 0) ? 0 : dd) * NH + gb;
        float2 g1[12];
        if (doB) {                                      // G1 in flight across A+barrier
#pragma unroll
            for (int u = 0; u < 12; ++u)
                g1[u] = ((const float2*)(rb + (size_t)u * 31 * NH))[lane];
        }
        __builtin_amdgcn_sched_barrier(0);

        if (w == 0 && i > 0) {
            // ---- Phase A (wave 0 only): fixed 32 taps, both rows; j>=i taps
            // are exact zeros (masked W1t / xr = 0)
            const int su = goff + lane;
            float bz = b1s[su];
            float w1v[32];
#pragma unroll
            for (int j = 0; j < 32; ++j) w1v[j] = W1t[j * W1T_STRIDE + su];
            float zA0 = bz, zA1 = 0, zA2 = 0, zA3 = 0;
            float zB0 = bz, zB1 = 0, zB2 = 0, zB3 = 0;
#pragma unroll
            for (int j = 0; j < 32; j += 4) {
                zA0 = fmaf(__shfl(xr0, j + 0, 64), w1v[j + 0], zA0);
                zB0 = fmaf(__shfl(xr1, j + 0, 64), w1v[j + 0], zB0);
                zA1 = fmaf(__shfl(xr0, j + 1, 64), w1v[j + 1], zA1);
                zB1 = fmaf(__shfl(xr1, j + 1, 64), w1v[j + 1], zB1);
                zA2 = fmaf(__shfl(xr0, j + 2, 64), w1v[j + 2], zA2);
                zB2 = fmaf(__shfl(xr1, j + 2, 64), w1v[j + 2], zB2);
                zA3 = fmaf(__shfl(xr0, j + 3, 64), w1v[j + 3], zA3);
                zB3 = fmaf(__shfl(xr1, j + 3, 64), w1v[j + 3], zB3);
            }
            if (lane < 36) {
                const bool ok = lane < cnt;
                a1s[lane][0] = ok ? fmaxf((zA0 + zA1) + (zA2 + zA3), 0.f) : 0.f;
                a1s[lane][1] = ok ? fmaxf((zB0 + zB1) + (zB2 + zB3), 0.f) : 0.f;
            }
        }
        __syncthreads();                                // barrier 1: a1 ready

        if (doB) {
            float2 g2[12];
#pragma unroll
            for (int u = 0; u < 12; ++u)
                g2[u] = ((const float2*)(rb + (size_t)(12 + u) * 31 * NH))[lane];
            __builtin_amdgcn_sched_barrier(0);
#pragma unroll
            for (int u = 0; u < 12; ++u) {              // consume G1
                float2 av = *(const float2*)&a1s[u][0]; // LDS broadcast
                acc0.x = fmaf(av.x, g1[u].x, acc0.x);
                acc0.y = fmaf(av.x, g1[u].y, acc0.y);
                acc1.x = fmaf(av.y, g1[u].x, acc1.x);
                acc1.y = fmaf(av.y, g1[u].y, acc1.y);
            }
            __builtin_amdgcn_sched_barrier(0);
            float2 g3[10];
#pragma unroll
            for (int u = 0; u < 10; ++u)
                g3[u] = ((const float2*)(rb + (size_t)(24 + u) * 31 * NH))[lane];
            __builtin_amdgcn_sched_barrier(0);
#pragma unroll
            for (int u = 0; u < 12; ++u) {              // consume G2
                float2 av = *(const float2*)&a1s[12 + u][0];
                acc0.x = fmaf(av.x, g2[u].x, acc0.x);
                acc0.y = fmaf(av.x, g2[u].y, acc0.y);
                acc1.x = fmaf(av.y, g2[u].x, acc1.x);
                acc1.y = fmaf(av.y, g2[u].y, acc1.y);
            }
            __builtin_amdgcn_sched_barrier(0);
#pragma unroll
            for (int u = 0; u < 10; ++u) {              // consume G3
                float2 av = *(const float2*)&a1s[24 + u][0];
                acc0.x = fmaf(av.x, g3[u].x, acc0.x);
                acc0.y = fmaf(av.x, g3[u].y, acc0.y);
                acc1.x = fmaf(av.y, g3[u].x, acc1.x);
                acc1.y = fmaf(av.y, g3[u].y, acc1.y);
            }
        }

        // ---- Phase C: slice partials (W3s zeros beyond prefix keep it exact)
        float s00 = 0, s01 = 0, s10 = 0, s11 = 0;
        if (doC) {
            float h0 = fmaxf(acc0.x, 0.f), h1 = fmaxf(acc0.y, 0.f);
            s00 = fmaf(wa.x, h0, wa.y * h1);
            s01 = fmaf(wb.x, h0, wb.y * h1);
            h0 = fmaxf(acc1.x, 0.f); h1 = fmaxf(acc1.y, 0.f);
            s10 = fmaf(wa.x, h0, wa.y * h1);
            s11 = fmaf(wb.x, h0, wb.y * h1);
#pragma unroll
            for (int m = 32; m >= 1; m >>= 1) {
                s00 += __shfl_xor(s00, m, 64); s01 += __shfl_xor(s01, m, 64);
                s10 += __shfl_xor(s10, m, 64); s11 += __shfl_xor(s11, m, 64);
            }
        }
        if (lane == 0)
            *((float4*)&part[i & 1][w][0]) = make_float4(s00, s01, s10, s11);
        __syncthreads();                                // barrier 2: partials ready

        // ---- combine (replicated in all lanes/waves -> identical xr update)
        const float* pb = &part[i & 1][0][0];
        float4 q = ((const float4*)pb)[0];
#pragma unroll
        for (int ww = 1; ww < 8; ++ww) {
            float4 tq = ((const float4*)pb)[ww];
            q.x += tq.x; q.y += tq.y; q.z += tq.z; q.w += tq.w;
        }
        float bi  = __shfl(b3v, i, 64);
        float bia = __shfl(b3v, NI + i, 64);
        float p00 = q.x + bi,  p01 = q.y + bia;
        float p10 = q.z + bi,  p11 = q.w + bia;
        float e20 = __expf(2.f * fminf(p01, 15.f));     // tanh; exact sat both ends
        float ta0 = (e20 - 1.f) / (e20 + 1.f);
        float x0  = fmaf(__shfl(xin0, i, 64), __expf(ta0), p00);
        float e21 = __expf(2.f * fminf(p11, 15.f));
        float ta1 = (e21 - 1.f) / (e21 + 1.f);
        float x1  = fmaf(__shfl(xin1, i, 64), __expf(ta1), p10);
        J0 -= ta0; J1 -= ta1;
        if (lane == i) { xr0 = x0; xr1 = x1; }
    }

    if (w == 0) {
        if (lane < NI) {
            out[row0 * NI + lane]       = xr0;
            out[(row0 + 1) * NI + lane] = xr1;
        }
        if (lane == 0) {
            out[NB * NI + row0]     = J0;
            out[NB * NI + row0 + 1] = J1;
        }
    }
}

extern "C" void kernel_launch(void* const* d_in, const int* in_sizes, int n_in,
                              void* d_out, int out_size, void* d_ws, size_t ws_size,
                              hipStream_t stream) {
    const float* inputs = (const float*)d_in[0];
    const float* W1     = (const float*)d_in[1];
    const float* b1     = (const float*)d_in[2];
    const float* W2     = (const float*)d_in[3];
    const float* b2     = (const float*)d_in[4];
    const float* W3     = (const float*)d_in[5];
    const float* b3     = (const float*)d_in[6];
    float* out = (float*)d_out;
    float* ws  = (float*)d_ws;

    prep_all<<<155, 256, 0, stream>>>(W1, b1, W2, b2, W3, ws);
    made_scan<<<NB / 2, 512, 0, stream>>>(inputs, b3, ws, out);
}

// Round 10
// 185.607 us; speedup vs baseline: 1.2420x; 1.2420x over previous
//
#include <hip/hip_runtime.h>
#include <math.h>

#define NI   32
#define NH   1024
#define NB   1024

// ws layout (floats). g-axis (h2 units) degree-SORTED (suffix skip); h1-axis NATURAL.
//   W1t [32][1056] : W1t[j][s] = m1-masked W1[orig(s)][j], s sorted (stride-padded)
//   b1s [1056]     : sorted b1 (overread lanes masked)
//   b2s [1024]     : sorted b2
//   W3s [64][1024] : m3-masked, sorted columns
//   W2t [1054][1024]: W2t[oh][sg] = m2-masked W2[orig(sg)][oh]; rows natural oh,
//                     +30 pad rows for u-overrun loads (x0.0, 0xAA = finite)
#define W1T_STRIDE 1056
#define OFF_W1T 0
#define OFF_B1S (32 * W1T_STRIDE)          // 33792
#define OFF_B2S (OFF_B1S + W1T_STRIDE)     // 34848
#define OFF_W3S (OFF_B2S + NH)             // 35872
#define OFF_W2T (OFF_W3S + 64 * NH)        // 101408
// total = 101408 + 1054*1024 = 1180704 floats (~4.72 MB)

// degree class d: units h = d, d+31, ... ; d=0 has 34 units, d>=1 has 33.
__device__ __forceinline__ int base_of(int d) { return (d == 0) ? 0 : 33 * d + 1; }

// ---- prep: W2 per-(class, 64-oh-chunk) transpose. 496 blocks (~2/CU).
// Reads: 64-float contiguous runs; writes: 33/34-float contiguous runs.
template <int CNT>
__device__ __forceinline__ void prep_w2_cls(int d, int oh0, const float* __restrict__ W2,
                                            float* __restrict__ ws, int t,
                                            float (*tile)[65]) {
    const int bse = base_of(d);
#pragma unroll 1
    for (int e = t; e < CNT * 64; e += 256) {       // coalesced reads
        int k = e >> 6, c = e & 63;
        int og = d + 31 * k;
        tile[k][c] = W2[(size_t)og * NH + oh0 + c];
    }
    __syncthreads();
#pragma unroll 1
    for (int e = t; e < 64 * CNT; e += 256) {       // contiguous CNT-float write runs
        int oh_l = e / CNT;                         // constexpr CNT -> magic mul
        int k = e - oh_l * CNT;
        int oh = oh0 + oh_l;
        float v = (d >= (oh % 31)) ? tile[k][oh_l] : 0.0f;
        ws[OFF_W2T + (size_t)oh * NH + bse + k] = v;
    }
}

template <int CNT>
__device__ __forceinline__ void prep_small_cls(int d, const float* __restrict__ W1,
        const float* __restrict__ b1, const float* __restrict__ b2,
        const float* __restrict__ W3, float* __restrict__ ws, int t) {
    const int bse = base_of(d);
#pragma unroll 1
    for (int e = t; e < 64 * CNT; e += 256) {       // W3s
        int o = e / CNT, k = e - o * CNT;
        int og = d + 31 * k;
        float v = (((o & 31) - 1) >= d) ? W3[(size_t)o * NH + og] : 0.0f;
        ws[OFF_W3S + (size_t)o * NH + bse + k] = v;
    }
#pragma unroll 1
    for (int e = t; e < 32 * CNT; e += 256) {       // W1t
        int j = e / CNT, k = e - j * CNT;
        int og = d + 31 * k;
        float v = (d >= j) ? W1[og * NI + j] : 0.0f;
        ws[OFF_W1T + j * W1T_STRIDE + bse + k] = v;
    }
    if (t < CNT) {                                  // biases
        int og = d + 31 * t;
        ws[OFF_B1S + bse + t] = b1[og];
        ws[OFF_B2S + bse + t] = b2[og];
    }
}

__global__ __launch_bounds__(256) void prep_all(const float* __restrict__ W1,
        const float* __restrict__ b1, const float* __restrict__ W2,
        const float* __restrict__ b2, const float* __restrict__ W3,
        float* __restrict__ ws) {
    __shared__ float tile[34][65];
    const int bid = blockIdx.x, t = threadIdx.x;
    if (bid < 496) {                                 // 31 classes x 16 oh-chunks
        int d = bid >> 4, oh0 = (bid & 15) * 64;
        if (d == 0) prep_w2_cls<34>(0, oh0, W2, ws, t, tile);
        else        prep_w2_cls<33>(d, oh0, W2, ws, t, tile);
    } else {                                         // 31 classes: W3s/W1t/biases
        int d = bid - 496;
        if (d == 0) prep_small_cls<34>(0, W1, b1, b2, W3, ws, t);
        else        prep_small_cls<33>(d, W1, b1, b2, W3, ws, t);
    }
}

// Block = 2 batch rows x 4 slice-waves (float4/lane). 512 blocks = 2/CU,
// 2 waves/SIMD. Slice ownership XOR-rotated by block parity so co-resident
// blocks pair complementary slices per SIMD ({0,3},{1,2}: 40/40 B-active
// wave-steps vs 62 unrotated). B's 34 panel loads in 3 sched-fenced groups.
__global__ __launch_bounds__(256, 2) void made_scan(
        const float* __restrict__ inputs,
        const float* __restrict__ b3,
        const float* __restrict__ ws,
        float* __restrict__ out) {
    __shared__ float part[2][4][4];     // [buf][wave][s00,s01,s10,s11]

    const int lane = threadIdx.x & 63;
    const int w    = threadIdx.x >> 6;
    const int pairity = ((blockIdx.x >> 8) ^ blockIdx.x) & 1;
    const int q    = w ^ (pairity * 3); // slice index (SIMD w hosts slice q)
    const int gb   = q * 256;           // sorted-g slice base
    const int row0 = blockIdx.x * 2;

    const float* W1t = ws + OFF_W1T;
    const float* b1s = ws + OFF_B1S;
    const float* b2s = ws + OFF_B2S;
    const float* W3s = ws + OFF_W3S;
    const float* W2t = ws + OFF_W2T;

    float4 acc0 = ((const float4*)(b2s + gb))[lane];   // z2 slice, rows 0/1
    float4 acc1 = acc0;
    float xin0 = (lane < NI) ? inputs[row0 * NI + lane] : 0.0f;
    float xin1 = (lane < NI) ? inputs[(row0 + 1) * NI + lane] : 0.0f;
    float b3v  = b3[lane];
    float xr0 = 0.f, xr1 = 0.f, J0 = 0.f, J1 = 0.f;    // x_j in lane j

#pragma unroll 1
    for (int i = 0; i < NI; ++i) {
        const int dd   = i - 1;
        const int goff = (i <= 1) ? 0 : (33 * i - 32);  // base(i-1)
        const int cnt  = (i == 1) ? 34 : 33;
        const int L    = 33 * i + 1;                    // base(i), i>=1
        const bool doB = (i > 0) && (gb + 256 > goff);
        const bool doC = (i > 0) && (gb < L);

        float4 wa = make_float4(0, 0, 0, 0), wb = make_float4(0, 0, 0, 0);
        if (doC) {                                      // C weights: issue early
            wa = ((const float4*)(W3s + (size_t)i * NH + gb))[lane];
            wb = ((const float4*)(W3s + (size_t)(NI + i) * NH + gb))[lane];
        }

        if (doB) {
            const int su = goff + lane;                 // sorted unit idx for lane
            float bz = b1s[su];
            float w1v[32];
#pragma unroll
            for (int j = 0; j < 32; ++j) w1v[j] = W1t[j * W1T_STRIDE + su];

            const float* rb = W2t + (size_t)dd * NH + gb;   // row oh = dd + 31u
            float4 g1[12];
#pragma unroll
            for (int u = 0; u < 12; ++u)
                g1[u] = ((const float4*)(rb + (size_t)u * 31 * NH))[lane];
            __builtin_amdgcn_sched_barrier(0);

            // ---- Phase A (2 rows): fixed 32 taps; j>=i taps are exact zeros
            float zA0 = bz, zA1 = 0, zA2 = 0, zA3 = 0;
            float zB0 = bz, zB1 = 0, zB2 = 0, zB3 = 0;
#pragma unroll
            for (int j = 0; j < 32; j += 4) {
                zA0 = fmaf(__shfl(xr0, j + 0, 64), w1v[j + 0], zA0);
                zB0 = fmaf(__shfl(xr1, j + 0, 64), w1v[j + 0], zB0);
                zA1 = fmaf(__shfl(xr0, j + 1, 64), w1v[j + 1], zA1);
                zB1 = fmaf(__shfl(xr1, j + 1, 64), w1v[j + 1], zB1);
                zA2 = fmaf(__shfl(xr0, j + 2, 64), w1v[j + 2], zA2);
                zB2 = fmaf(__shfl(xr1, j + 2, 64), w1v[j + 2], zB2);
                zA3 = fmaf(__shfl(xr0, j + 3, 64), w1v[j + 3], zA3);
                zB3 = fmaf(__shfl(xr1, j + 3, 64), w1v[j + 3], zB3);
            }
            const bool ok = lane < cnt;
            float a0 = ok ? fmaxf((zA0 + zA1) + (zA2 + zA3), 0.f) : 0.f;
            float a1 = ok ? fmaxf((zB0 + zB1) + (zB2 + zB3), 0.f) : 0.f;
            __builtin_amdgcn_sched_barrier(0);

            float4 g2[12];
#pragma unroll
            for (int u = 0; u < 12; ++u)
                g2[u] = ((const float4*)(rb + (size_t)(12 + u) * 31 * NH))[lane];
            __builtin_amdgcn_sched_barrier(0);
#pragma unroll
            for (int u = 0; u < 12; ++u) {              // consume G1
                float c0 = __shfl(a0, u, 64), c1 = __shfl(a1, u, 64);
                acc0.x = fmaf(c0, g1[u].x, acc0.x); acc0.y = fmaf(c0, g1[u].y, acc0.y);
                acc0.z = fmaf(c0, g1[u].z, acc0.z); acc0.w = fmaf(c0, g1[u].w, acc0.w);
                acc1.x = fmaf(c1, g1[u].x, acc1.x); acc1.y = fmaf(c1, g1[u].y, acc1.y);
                acc1.z = fmaf(c1, g1[u].z, acc1.z); acc1.w = fmaf(c1, g1[u].w, acc1.w);
            }
            __builtin_amdgcn_sched_barrier(0);

            float4 g3[10];
#pragma unroll
            for (int u = 0; u < 10; ++u)
                g3[u] = ((const float4*)(rb + (size_t)(24 + u) * 31 * NH))[lane];
            __builtin_amdgcn_sched_barrier(0);
#pragma unroll
            for (int u = 0; u < 12; ++u) {              // consume G2
                float c0 = __shfl(a0, 12 + u, 64), c1 = __shfl(a1, 12 + u, 64);
                acc0.x = fmaf(c0, g2[u].x, acc0.x); acc0.y = fmaf(c0, g2[u].y, acc0.y);
                acc0.z = fmaf(c0, g2[u].z, acc0.z); acc0.w = fmaf(c0, g2[u].w, acc0.w);
                acc1.x = fmaf(c1, g2[u].x, acc1.x); acc1.y = fmaf(c1, g2[u].y, acc1.y);
                acc1.z = fmaf(c1, g2[u].z, acc1.z); acc1.w = fmaf(c1, g2[u].w, acc1.w);
            }
            __builtin_amdgcn_sched_barrier(0);
#pragma unroll
            for (int u = 0; u < 10; ++u) {              // consume G3
                float c0 = __shfl(a0, 24 + u, 64), c1 = __shfl(a1, 24 + u, 64);
                acc0.x = fmaf(c0, g3[u].x, acc0.x); acc0.y = fmaf(c0, g3[u].y, acc0.y);
                acc0.z = fmaf(c0, g3[u].z, acc0.z); acc0.w = fmaf(c0, g3[u].w, acc0.w);
                acc1.x = fmaf(c1, g3[u].x, acc1.x); acc1.y = fmaf(c1, g3[u].y, acc1.y);
                acc1.z = fmaf(c1, g3[u].z, acc1.z); acc1.w = fmaf(c1, g3[u].w, acc1.w);
            }
        }

        // ---- Phase C: slice partials (W3s zeros beyond prefix keep it exact)
        float s00 = 0, s01 = 0, s10 = 0, s11 = 0;
        if (doC) {
            float hx, hy, hz, hw;
            hx = fmaxf(acc0.x, 0.f); hy = fmaxf(acc0.y, 0.f);
            hz = fmaxf(acc0.z, 0.f); hw = fmaxf(acc0.w, 0.f);
            s00 = fmaf(wa.x, hx, fmaf(wa.y, hy, fmaf(wa.z, hz, wa.w * hw)));
            s01 = fmaf(wb.x, hx, fmaf(wb.y, hy, fmaf(wb.z, hz, wb.w * hw)));
            hx = fmaxf(acc1.x, 0.f); hy = fmaxf(acc1.y, 0.f);
            hz = fmaxf(acc1.z, 0.f); hw = fmaxf(acc1.w, 0.f);
            s10 = fmaf(wa.x, hx, fmaf(wa.y, hy, fmaf(wa.z, hz, wa.w * hw)));
            s11 = fmaf(wb.x, hx, fmaf(wb.y, hy, fmaf(wb.z, hz, wb.w * hw)));
#pragma unroll
            for (int m = 32; m >= 1; m >>= 1) {
                s00 += __shfl_xor(s00, m, 64); s01 += __shfl_xor(s01, m, 64);
                s10 += __shfl_xor(s10, m, 64); s11 += __shfl_xor(s11, m, 64);
            }
        }
        if (lane == 0)
            *((float4*)&part[i & 1][w][0]) = make_float4(s00, s01, s10, s11);
        __syncthreads();

        // ---- combine (replicated in all lanes/waves -> identical xr update)
        const float* pb = &part[i & 1][0][0];
        float4 q0 = ((const float4*)pb)[0], q1 = ((const float4*)pb)[1];
        float4 q2 = ((const float4*)pb)[2], q3 = ((const float4*)pb)[3];
        float bi  = __shfl(b3v, i, 64);
        float bia = __shfl(b3v, NI + i, 64);
        float p00 = ((q0.x + q1.x) + (q2.x + q3.x)) + bi;
        float p01 = ((q0.y + q1.y) + (q2.y + q3.y)) + bia;
        float p10 = ((q0.z + q1.z) + (q2.z + q3.z)) + bi;
        float p11 = ((q0.w + q1.w) + (q2.w + q3.w)) + bia;
        float e20 = __expf(2.f * fminf(p01, 15.f));     // tanh; exact sat both ends
        float ta0 = (e20 - 1.f) / (e20 + 1.f);
        float x0  = fmaf(__shfl(xin0, i, 64), __expf(ta0), p00);
        float e21 = __expf(2.f * fminf(p11, 15.f));
        float ta1 = (e21 - 1.f) / (e21 + 1.f);
        float x1  = fmaf(__shfl(xin1, i, 64), __expf(ta1), p10);
        J0 -= ta0; J1 -= ta1;
        if (lane == i) { xr0 = x0; xr1 = x1; }
    }

    if (w == 0) {
        if (lane < NI) {
            out[row0 * NI + lane]       = xr0;
            out[(row0 + 1) * NI + lane] = xr1;
        }
        if (lane == 0) {
            out[NB * NI + row0]     = J0;
            out[NB * NI + row0 + 1] = J1;
        }
    }
}

extern "C" void kernel_launch(void* const* d_in, const int* in_sizes, int n_in,
                              void* d_out, int out_size, void* d_ws, size_t ws_size,
                              hipStream_t stream) {
    const float* inputs = (const float*)d_in[0];
    const float* W1     = (const float*)d_in[1];
    const float* b1     = (const float*)d_in[2];
    const float* W2     = (const float*)d_in[3];
    const float* b2     = (const float*)d_in[4];
    const float* W3     = (const float*)d_in[5];
    const float* b3     = (const float*)d_in[6];
    float* out = (float*)d_out;
    float* ws  = (float*)d_ws;

    prep_all<<<527, 256, 0, stream>>>(W1, b1, W2, b2, W3, ws);
    made_scan<<<NB / 2, 256, 0, stream>>>(inputs, b3, ws, out);
}